// Round 9
// baseline (9601.421 us; speedup 1.0000x reference)
//
#include <hip/hip_runtime.h>
#include <math.h>

#define NSWEEP_MAX 16
#define T2_TOL 1e-8f    // exit when max dpq^2/(dpp*dqq) below this
#define EPS2 1e-10f     // lambda clamp 1e-5 => lambda^2 clamp 1e-10

// One-sided Jacobi on G = S (SPD): orthogonalize columns; at convergence
// G = U diag(lambda), U = eigenvectors, lambda = column norms. One 64-lane
// wave per matrix; lane l holds column l in 64 VGPRs. XOR pairing: round m
// rotates pairs {l, l^m}.
//
// DS-pipe diet (rounds 5-7: DS pipe is the binding resource, VALU 37% idle):
//  (a) DS rounds fetch the partner column via inline-asm ds_bpermute_b32 —
//      inline asm cannot be rematerialized, so the 64 fetched values stay
//      register-resident across dot->coeff->rotate (the builtin was being
//      re-fetched: VGPR_Count stuck at 80 = a second 64-bpermute pass).
//      s_waitcnt lgkmcnt(0) + sched_barrier(0) per methodology rule #18.
//  (b) 23 of 63 rounds run entirely on the VALU pipe: lane^m with
//      (m&15) in {0,1,2,3,7,15} is a DPP pattern (quad_perm / half-mirror /
//      mirror); bits 4/5 are gfx950 permlane16/32 SELF-swaps:
//      v_permlane16_swap_b32 vX, vX exchanges lanes 0-15<->16-31 and
//      32-47<->48-63 within ONE register == the XOR-16 permutation,
//      regardless of the instruction's vdst/vsrc direction convention
//      (round-8 failure: two-register swap + cndmask guessed the direction
//      wrong; self-swap is direction-agnostic since the write sets are
//      disjoint lanes of the same register).
//
// TIE-SAFE rotation: both lanes of a pair evaluate the rotation in the
// CANONICAL orientation (low-lane = "p"): tau = (d_hi - d_lo) * rcp(2*dpq).
// Operands and order identical on both lanes -> bitwise-identical
// tau/tt/cc/ss; only the application sign differs:
//   es    = isLow ? -ss : +ss     (g' = cc*g_own + es*g_partner)
//   t_own = isLow ? +tt : -tt     (dpp' = dpp - t_own*dpq)
// The 4-way split dot keeps pair symmetry: fma(a,b,c)==fma(b,a,c) bitwise
// and both lanes accumulate the same products in the same order.

__device__ __forceinline__ float rdlane_f(float x, int l) {
    return __int_as_float(__builtin_amdgcn_readlane(__float_as_int(x), l));
}

// DPP ctrl encodings: quad_perm[a,b,c,d] = a|b<<2|c<<4|d<<6
#define DPP_X1 0xB1   // [1,0,3,2]  lane^1
#define DPP_X2 0x4E   // [2,3,0,1]  lane^2
#define DPP_X3 0x1B   // [3,2,1,0]  lane^3
#define DPP_X7 0x141  // row_half_mirror: lane^7
#define DPP_X15 0x140 // row_mirror:      lane^15

__device__ __forceinline__ int dpp_mov(int x, int ctrl) {
    switch (ctrl) {
        case DPP_X1:  return __builtin_amdgcn_update_dpp(0, x, DPP_X1, 0xF, 0xF, true);
        case DPP_X2:  return __builtin_amdgcn_update_dpp(0, x, DPP_X2, 0xF, 0xF, true);
        case DPP_X3:  return __builtin_amdgcn_update_dpp(0, x, DPP_X3, 0xF, 0xF, true);
        case DPP_X7:  return __builtin_amdgcn_update_dpp(0, x, DPP_X7, 0xF, 0xF, true);
        default:      return __builtin_amdgcn_update_dpp(0, x, DPP_X15, 0xF, 0xF, true);
    }
}
__device__ __forceinline__ float swap16_self(float x) {
    asm("v_permlane16_swap_b32 %0, %0" : "+v"(x));
    return x;  // x[lane] = old x[lane^16], both direction conventions
}
__device__ __forceinline__ float swap32_self(float x) {
    asm("v_permlane32_swap_b32 %0, %0" : "+v"(x));
    return x;  // x[lane] = old x[lane^32]
}

__global__ __launch_bounds__(64, 2) void spdlog_onesided(
    const float* __restrict__ S, float* __restrict__ Out, int nmat) {
    __shared__ float X[64][64];  // 16 KB, reconstruction only
    const int lane = threadIdx.x;
    const int b = blockIdx.x;
    if (b >= nmat) return;
    const float* Sb = S + (size_t)b * 4096;
    float* Ob = Out + (size_t)b * 4096;

    // ---- load column `lane`: g[s] = S[s][lane] (coalesced across lanes)
    float g[64];
    #pragma unroll 64
    for (int s = 0; s < 64; ++s) g[s] = Sb[s * 64 + lane];

    float dpp = 0.0f;

    #pragma unroll 1
    for (int sweep = 0; sweep < NSWEEP_MAX; ++sweep) {
        // refresh Gram diagonal from actual column (kills drift)
        float d0 = 0.0f, d1 = 0.0f, d2 = 0.0f, d3 = 0.0f;
        #pragma unroll 16
        for (int s = 0; s < 64; s += 4) {
            d0 = fmaf(g[s], g[s], d0);
            d1 = fmaf(g[s + 1], g[s + 1], d1);
            d2 = fmaf(g[s + 2], g[s + 2], d2);
            d3 = fmaf(g[s + 3], g[s + 3], d3);
        }
        dpp = (d0 + d1) + (d2 + d3);

        float maxt2 = 0.0f;
        #pragma unroll 1
        for (int m = 1; m < 64; ++m) {
            const int xl = lane ^ m;
            const bool isLow = lane < xl;
            const int lo = m & 15;
            const bool valu = (lo == 0) | (lo == 1) | (lo == 2) |
                              (lo == 3) | (lo == 7) | (lo == 15);
            float pr[64];
            float pd;
            if (valu) {
                // ---- VALU fetch. pd chain interleaved between the pr
                // loops so dependent same-register ops sit >=64 apart.
                int ctrl = (lo == 1) ? DPP_X1 : (lo == 2) ? DPP_X2 :
                           (lo == 3) ? DPP_X3 : (lo == 7) ? DPP_X7 : DPP_X15;
                int xpd = __float_as_int(dpp);
                if (lo) xpd = dpp_mov(xpd, ctrl);
                if (lo) {
                    #pragma unroll 64
                    for (int s = 0; s < 64; ++s)
                        pr[s] = __int_as_float(
                            dpp_mov(__float_as_int(g[s]), ctrl));
                } else {
                    #pragma unroll 64
                    for (int s = 0; s < 64; ++s) pr[s] = g[s];
                }
                if (m & 16) {
                    float t = __int_as_float(xpd);
                    xpd = __float_as_int(swap16_self(t));
                    #pragma unroll 64
                    for (int s = 0; s < 64; ++s) pr[s] = swap16_self(pr[s]);
                }
                if (m & 32) {
                    float t = __int_as_float(xpd);
                    xpd = __float_as_int(swap32_self(t));
                    #pragma unroll 64
                    for (int s = 0; s < 64; ++s) pr[s] = swap32_self(pr[s]);
                }
                pd = __int_as_float(xpd);
            } else {
                // ---- DS fetch: inline-asm ds_bpermute (not remat-able)
                const int idx = xl << 2;
                #pragma unroll 64
                for (int s = 0; s < 64; ++s)
                    asm("ds_bpermute_b32 %0, %1, %2"
                        : "=v"(pr[s]) : "v"(idx), "v"(g[s]) : "memory");
                asm("ds_bpermute_b32 %0, %1, %2"
                    : "=v"(pd) : "v"(idx), "v"(dpp) : "memory");
                asm volatile("s_waitcnt lgkmcnt(0)" ::: "memory");
                __builtin_amdgcn_sched_barrier(0);
            }
            // ---- lane-local Gram cross term (4-way split, pair-symmetric)
            float a0 = 0.0f, a1 = 0.0f, a2 = 0.0f, a3 = 0.0f;
            #pragma unroll 16
            for (int s = 0; s < 64; s += 4) {
                a0 = fmaf(g[s], pr[s], a0);
                a1 = fmaf(g[s + 1], pr[s + 1], a1);
                a2 = fmaf(g[s + 2], pr[s + 2], a2);
                a3 = fmaf(g[s + 3], pr[s + 3], a3);
            }
            const float dpq = (a0 + a1) + (a2 + a3);
            const float d_lo = isLow ? dpp : pd;
            const float d_hi = isLow ? pd : dpp;
            // convergence metric (relative Gram off-diagonal, pre-rotation)
            const float t2 = dpq * dpq * __builtin_amdgcn_rcpf(dpp * pd);
            maxt2 = fmaxf(maxt2, t2);
            // ---- canonical rotation (identical bits on both lanes)
            const float tau = (d_hi - d_lo) * __builtin_amdgcn_rcpf(2.0f * dpq);
            const float sq = __builtin_amdgcn_sqrtf(fmaf(tau, tau, 1.0f));
            float tt = __builtin_amdgcn_rcpf(fabsf(tau) + sq);
            tt = copysignf(tt, tau);
            float cc = __builtin_amdgcn_rsqf(fmaf(tt, tt, 1.0f));
            float ss = tt * cc;
            const bool tiny = fabsf(dpq) < 1e-30f;
            cc = tiny ? 1.0f : cc;
            ss = tiny ? 0.0f : ss;
            tt = tiny ? 0.0f : tt;
            const float es = isLow ? -ss : ss;
            const float t_own = isLow ? tt : -tt;
            dpp = fmaf(-t_own, dpq, dpp);  // exact diagonal Gram update
            // ---- register-only rotate (uses the live pr[])
            #pragma unroll 64
            for (int s = 0; s < 64; ++s) g[s] = fmaf(cc, g[s], es * pr[s]);
        }
        // ---- wave max of maxt2
        maxt2 = fmaxf(maxt2, __shfl_xor(maxt2, 1));
        maxt2 = fmaxf(maxt2, __shfl_xor(maxt2, 2));
        maxt2 = fmaxf(maxt2, __shfl_xor(maxt2, 4));
        maxt2 = fmaxf(maxt2, __shfl_xor(maxt2, 8));
        maxt2 = fmaxf(maxt2, __shfl_xor(maxt2, 16));
        maxt2 = fmaxf(maxt2, __shfl_xor(maxt2, 32));
        if (maxt2 < T2_TOL) break;  // wave-uniform
    }

    // ---- fresh column norm^2 -> eigenvalue; clamp matches ref (on lambda)
    float dfin = 0.0f;
    #pragma unroll 64
    for (int s = 0; s < 64; ++s) dfin = fmaf(g[s], g[s], dfin);
    const float w = 0.5f * logf(fmaxf(dfin, EPS2));
    const float rs = __builtin_amdgcn_rsqf(fmaxf(dfin, 1e-20f));

    // ---- reconstruction: O = U diag(w) U^T, U columns = g*rs
    #pragma unroll 64
    for (int s = 0; s < 64; ++s) X[s][lane] = g[s] * rs;  // lane-private col
    __syncthreads();
    float uw[64];
    {
        const float4* rowp = (const float4*)&X[lane][0];  // own row of U
        #pragma unroll 16
        for (int gq = 0; gq < 16; ++gq) {
            const float4 q = rowp[gq];
            uw[4 * gq + 0] = q.x;
            uw[4 * gq + 1] = q.y;
            uw[4 * gq + 2] = q.z;
            uw[4 * gq + 3] = q.w;
        }
    }
    #pragma unroll 64
    for (int c = 0; c < 64; ++c) uw[c] *= rdlane_f(w, c);
    #pragma unroll 2
    for (int i = 0; i < 64; ++i) {
        const float4* Urow = (const float4*)&X[i][0];  // wave-uniform: bcast
        float acc = 0.0f;
        #pragma unroll 16
        for (int gq = 0; gq < 16; ++gq) {
            const float4 q = Urow[gq];
            acc = fmaf(q.x, uw[4 * gq + 0], acc);
            acc = fmaf(q.y, uw[4 * gq + 1], acc);
            acc = fmaf(q.z, uw[4 * gq + 2], acc);
            acc = fmaf(q.w, uw[4 * gq + 3], acc);
        }
        Ob[i * 64 + lane] = acc;
    }
}

extern "C" void kernel_launch(void* const* d_in, const int* in_sizes, int n_in,
                              void* d_out, int out_size, void* d_ws, size_t ws_size,
                              hipStream_t stream) {
    const float* S = (const float*)d_in[0];
    float* Out = (float*)d_out;
    const int nmat = in_sizes[0] / 4096;
    spdlog_onesided<<<nmat, 64, 0, stream>>>(S, Out, nmat);
}

// Round 10
// 5835.889 us; speedup vs baseline: 1.6452x; 1.6452x over previous
//
#include <hip/hip_runtime.h>
#include <math.h>

#define NSWEEP_MAX 16
#define T2_TOL 1e-8f    // exit when max dpq^2/(dpp*dqq) below this
#define EPS2 1e-10f     // lambda clamp 1e-5 => lambda^2 clamp 1e-10

// One-sided Jacobi on G = S (SPD): orthogonalize columns; at convergence
// G = U diag(lambda), U = eigenvectors, lambda = column norms. One 64-lane
// wave per matrix; lane l holds column l in 64 VGPRs. XOR pairing: round m
// rotates pairs {l, l^m}.
//
// ALL-VALU partner fetch (rounds 5-9 showed the per-CU DS pipe is the
// binding resource at ~4.4cyc/wave-op while 4 SIMDs idle at 37%):
// lane^m decomposes into compile-time VALU permutes:
//   m&15: 1-2 DPP movs  — XOR1/2/3 = quad_perm 0xB1/0x4E/0x1B,
//         XOR7 = row_half_mirror 0x141, XOR15 = row_mirror 0x140,
//         XOR8 = row_ror:8 0x128 ((i+8)%16 == i^8), others = 2-compositions
//         (XOR masks compose: dppB(dppA(x)) fetches lane^(A^B)).
//   m&16 / m&32: v_permlane16/32_swap_b32 vX,vX self-swap == XOR16/XOR32
//         (HW-verified correct in round 9).
// Round 9's 2.2x regression was a RUNTIME dpp ctrl inside the unrolled
// loops (per-element 5-way branch tree). Here the wave-uniform switch(lo)
// dispatches to 16 bodies whose DPP ctrls are template constants — branch
// once per round, zero per-element overhead, ~2k instrs total.
//
// TIE-SAFE rotation: both lanes of a pair evaluate the rotation in the
// CANONICAL orientation (low-lane = "p"): tau = (d_hi - d_lo) * rcp(2*dpq).
// Operands and order identical on both lanes -> bitwise-identical
// tau/tt/cc/ss; only the application sign differs:
//   es    = isLow ? -ss : +ss     (g' = cc*g_own + es*g_partner)
//   t_own = isLow ? +tt : -tt     (dpp' = dpp - t_own*dpq)
// The 4-way split dot keeps pair symmetry: fma(a,b,c)==fma(b,a,c) bitwise
// and both lanes accumulate the same products in the same order.

template <int CTRL>
__device__ __forceinline__ int dpp1(int x) {
    return __builtin_amdgcn_update_dpp(0, x, CTRL, 0xF, 0xF, true);
}
__device__ __forceinline__ float swap16_self(float x) {
    asm("v_permlane16_swap_b32 %0, %0" : "+v"(x));
    return x;  // x[lane] = old x[lane^16]
}
__device__ __forceinline__ float swap32_self(float x) {
    asm("v_permlane32_swap_b32 %0, %0" : "+v"(x));
    return x;  // x[lane] = old x[lane^32]
}
__device__ __forceinline__ float rdlane_f(float x, int l) {
    return __int_as_float(__builtin_amdgcn_readlane(__float_as_int(x), l));
}

#define FETCH1(CTRL)                                                     \
    {                                                                    \
        _Pragma("unroll") for (int s = 0; s < 64; ++s)                   \
            pr[s] = __int_as_float(dpp1<CTRL>(__float_as_int(g[s])));    \
        pdv = __int_as_float(dpp1<CTRL>(__float_as_int(pdv)));           \
    }
#define FETCH2(C1, C2)                                                   \
    {                                                                    \
        _Pragma("unroll") for (int s = 0; s < 64; ++s)                   \
            pr[s] = __int_as_float(                                      \
                dpp1<C2>(dpp1<C1>(__float_as_int(g[s]))));               \
        pdv = __int_as_float(dpp1<C2>(dpp1<C1>(__float_as_int(pdv))));   \
    }

__global__ __launch_bounds__(64, 2) void spdlog_onesided(
    const float* __restrict__ S, float* __restrict__ Out, int nmat) {
    __shared__ float X[64][64];  // 16 KB, reconstruction only
    const int lane = threadIdx.x;
    const int b = blockIdx.x;
    if (b >= nmat) return;
    const float* Sb = S + (size_t)b * 4096;
    float* Ob = Out + (size_t)b * 4096;

    // ---- load column `lane`: g[s] = S[s][lane] (coalesced across lanes)
    float g[64];
    #pragma unroll 64
    for (int s = 0; s < 64; ++s) g[s] = Sb[s * 64 + lane];

    float dpp = 0.0f;

    #pragma unroll 1
    for (int sweep = 0; sweep < NSWEEP_MAX; ++sweep) {
        // refresh Gram diagonal from actual column (kills drift)
        float d0 = 0.0f, d1 = 0.0f, d2 = 0.0f, d3 = 0.0f;
        #pragma unroll 16
        for (int s = 0; s < 64; s += 4) {
            d0 = fmaf(g[s], g[s], d0);
            d1 = fmaf(g[s + 1], g[s + 1], d1);
            d2 = fmaf(g[s + 2], g[s + 2], d2);
            d3 = fmaf(g[s + 3], g[s + 3], d3);
        }
        dpp = (d0 + d1) + (d2 + d3);

        float maxt2 = 0.0f;
        #pragma unroll 1
        for (int m = 1; m < 64; ++m) {
            const int xl = lane ^ m;
            const bool isLow = lane < xl;
            const int lo = m & 15;
            float pr[64];
            float pdv = dpp;
            // ---- compile-time DPP bodies, wave-uniform dispatch on lo
            switch (lo) {
                case 0:
                    #pragma unroll
                    for (int s = 0; s < 64; ++s) pr[s] = g[s];
                    break;
                case 1:  FETCH1(0xB1) break;
                case 2:  FETCH1(0x4E) break;
                case 3:  FETCH1(0x1B) break;
                case 4:  FETCH2(0x1B, 0x141) break;  // 3^7
                case 5:  FETCH2(0x4E, 0x141) break;  // 2^7
                case 6:  FETCH2(0xB1, 0x141) break;  // 1^7
                case 7:  FETCH1(0x141) break;
                case 8:  FETCH1(0x128) break;        // row_ror:8 == XOR8
                case 9:  FETCH2(0xB1, 0x128) break;  // 1^8
                case 10: FETCH2(0x4E, 0x128) break;  // 2^8
                case 11: FETCH2(0x1B, 0x128) break;  // 3^8
                case 12: FETCH2(0x1B, 0x140) break;  // 3^15
                case 13: FETCH2(0x4E, 0x140) break;  // 2^15
                case 14: FETCH2(0xB1, 0x140) break;  // 1^15
                default: FETCH1(0x140) break;        // 15
            }
            if (m & 16) {
                #pragma unroll
                for (int s = 0; s < 64; ++s) pr[s] = swap16_self(pr[s]);
                pdv = swap16_self(pdv);
            }
            if (m & 32) {
                #pragma unroll
                for (int s = 0; s < 64; ++s) pr[s] = swap32_self(pr[s]);
                pdv = swap32_self(pdv);
            }
            const float pd = pdv;
            // ---- lane-local Gram cross term (4-way split, pair-symmetric)
            float a0 = 0.0f, a1 = 0.0f, a2 = 0.0f, a3 = 0.0f;
            #pragma unroll 16
            for (int s = 0; s < 64; s += 4) {
                a0 = fmaf(g[s], pr[s], a0);
                a1 = fmaf(g[s + 1], pr[s + 1], a1);
                a2 = fmaf(g[s + 2], pr[s + 2], a2);
                a3 = fmaf(g[s + 3], pr[s + 3], a3);
            }
            const float dpq = (a0 + a1) + (a2 + a3);
            const float d_lo = isLow ? dpp : pd;
            const float d_hi = isLow ? pd : dpp;
            // convergence metric (relative Gram off-diagonal, pre-rotation)
            const float t2 = dpq * dpq * __builtin_amdgcn_rcpf(dpp * pd);
            maxt2 = fmaxf(maxt2, t2);
            // ---- canonical rotation (identical bits on both lanes)
            const float tau = (d_hi - d_lo) * __builtin_amdgcn_rcpf(2.0f * dpq);
            const float sq = __builtin_amdgcn_sqrtf(fmaf(tau, tau, 1.0f));
            float tt = __builtin_amdgcn_rcpf(fabsf(tau) + sq);
            tt = copysignf(tt, tau);
            float cc = __builtin_amdgcn_rsqf(fmaf(tt, tt, 1.0f));
            float ss = tt * cc;
            const bool tiny = fabsf(dpq) < 1e-30f;
            cc = tiny ? 1.0f : cc;
            ss = tiny ? 0.0f : ss;
            tt = tiny ? 0.0f : tt;
            const float es = isLow ? -ss : ss;
            const float t_own = isLow ? tt : -tt;
            dpp = fmaf(-t_own, dpq, dpp);  // exact diagonal Gram update
            // ---- register-only rotate (uses the live pr[])
            #pragma unroll 64
            for (int s = 0; s < 64; ++s) g[s] = fmaf(cc, g[s], es * pr[s]);
        }
        // ---- wave max of maxt2
        maxt2 = fmaxf(maxt2, __shfl_xor(maxt2, 1));
        maxt2 = fmaxf(maxt2, __shfl_xor(maxt2, 2));
        maxt2 = fmaxf(maxt2, __shfl_xor(maxt2, 4));
        maxt2 = fmaxf(maxt2, __shfl_xor(maxt2, 8));
        maxt2 = fmaxf(maxt2, __shfl_xor(maxt2, 16));
        maxt2 = fmaxf(maxt2, __shfl_xor(maxt2, 32));
        if (maxt2 < T2_TOL) break;  // wave-uniform
    }

    // ---- fresh column norm^2 -> eigenvalue; clamp matches ref (on lambda)
    float dfin = 0.0f;
    #pragma unroll 64
    for (int s = 0; s < 64; ++s) dfin = fmaf(g[s], g[s], dfin);
    const float w = 0.5f * logf(fmaxf(dfin, EPS2));
    const float rs = __builtin_amdgcn_rsqf(fmaxf(dfin, 1e-20f));

    // ---- reconstruction: O = U diag(w) U^T, U columns = g*rs
    #pragma unroll 64
    for (int s = 0; s < 64; ++s) X[s][lane] = g[s] * rs;  // lane-private col
    __syncthreads();
    float uw[64];
    {
        const float4* rowp = (const float4*)&X[lane][0];  // own row of U
        #pragma unroll 16
        for (int gq = 0; gq < 16; ++gq) {
            const float4 q = rowp[gq];
            uw[4 * gq + 0] = q.x;
            uw[4 * gq + 1] = q.y;
            uw[4 * gq + 2] = q.z;
            uw[4 * gq + 3] = q.w;
        }
    }
    #pragma unroll 64
    for (int c = 0; c < 64; ++c) uw[c] *= rdlane_f(w, c);
    #pragma unroll 2
    for (int i = 0; i < 64; ++i) {
        const float4* Urow = (const float4*)&X[i][0];  // wave-uniform: bcast
        float acc = 0.0f;
        #pragma unroll 16
        for (int gq = 0; gq < 16; ++gq) {
            const float4 q = Urow[gq];
            acc = fmaf(q.x, uw[4 * gq + 0], acc);
            acc = fmaf(q.y, uw[4 * gq + 1], acc);
            acc = fmaf(q.z, uw[4 * gq + 2], acc);
            acc = fmaf(q.w, uw[4 * gq + 3], acc);
        }
        Ob[i * 64 + lane] = acc;
    }
}

extern "C" void kernel_launch(void* const* d_in, const int* in_sizes, int n_in,
                              void* d_out, int out_size, void* d_ws, size_t ws_size,
                              hipStream_t stream) {
    const float* S = (const float*)d_in[0];
    float* Out = (float*)d_out;
    const int nmat = in_sizes[0] / 4096;
    spdlog_onesided<<<nmat, 64, 0, stream>>>(S, Out, nmat);
}

// Round 11
// 4316.705 us; speedup vs baseline: 2.2242x; 1.3519x over previous
//
#include <hip/hip_runtime.h>
#include <math.h>

#define NSWEEP_MAX 16
#define T2_TOL 1e-8f    // converged when max dpq^2/(dpp*dqq) below this
#define EPS2 1e-10f     // lambda clamp 1e-5 => lambda^2 clamp 1e-10

// One-sided Jacobi on G = S (SPD), one 64-lane wave per 64x64 matrix,
// lane l holds column l in 64 VGPRs.
//
// GRAY-CODE pairing with a maintained partner copy:
//   rounds ordered m_i = i^(i>>1), i=1..63 (visits all m exactly once);
//   consecutive pairings differ by delta = i & -i (a single bit), so the
//   partner column for the next round is a ONE-OP XOR permute of the
//   maintained copy pr[] (DPP quad_perm/row_ror for bits 0-3, gfx950
//   v_permlane16/32_swap self-swap for bits 4/5 — all ctrls compile-time,
//   HW-verified in rounds 9/10). pr[] is updated locally after each
//   rotation (pr' = cc*pr - es*g_old == partner's own update, bitwise),
//   making it a loop-carried chain the compiler CANNOT rematerialize —
//   rounds 5-10 all failed to keep a fetched copy live (VGPR stuck at 80,
//   a hidden second fetch pass per round).
//   Cost: ~6 VALU ops/elem/round (dot 1, updates 4, permute ~1.13) with
//   zero DS-pipe traffic in the main loop.
//
// BITWISE pair-consistency (required so both lanes of a pair apply
// mirrored rotations): dpq via commuted fma (fma(a,b,c)==fma(b,a,c));
// canonical orientation tau = (d_hi-d_lo)*rcp(2dpq) identical on both
// lanes; es/t_own sign-split by isLow; the pr/pd update expressions are
// exact negation-mirrors of the partner's own updates. Invariant
// pr_l == g_{l^m}, pd_l == dpp_{l^m} holds bitwise by induction.
//
// Wave-uniform SKIP: if __all(t2 < T2_TOL) the round applies no rotation
// (identity — chain invariant preserved), saving the update block in
// late, mostly-converged sweeps.

template <int CTRL>
__device__ __forceinline__ int dpp1(int x) {
    return __builtin_amdgcn_update_dpp(0, x, CTRL, 0xF, 0xF, true);
}
__device__ __forceinline__ float dppf(float x, int) = delete;
template <int CTRL>
__device__ __forceinline__ float dppf1(float x) {
    return __int_as_float(dpp1<CTRL>(__float_as_int(x)));
}
__device__ __forceinline__ float swap16_self(float x) {
    asm("v_permlane16_swap_b32 %0, %0" : "+v"(x));
    return x;  // x[lane] = old x[lane^16]
}
__device__ __forceinline__ float swap32_self(float x) {
    asm("v_permlane32_swap_b32 %0, %0" : "+v"(x));
    return x;  // x[lane] = old x[lane^32]
}
__device__ __forceinline__ float rdlane_f(float x, int l) {
    return __int_as_float(__builtin_amdgcn_readlane(__float_as_int(x), l));
}

#define DPP_X1 0xB1   // quad_perm [1,0,3,2]  : lane^1
#define DPP_X2 0x4E   // quad_perm [2,3,0,1]  : lane^2
#define DPP_X3 0x1B   // quad_perm [3,2,1,0]  : lane^3
#define DPP_X7 0x141  // row_half_mirror      : lane^7
#define DPP_X8 0x128  // row_ror:8            : lane^8

__global__ __launch_bounds__(64, 2) void spdlog_onesided(
    const float* __restrict__ S, float* __restrict__ Out, int nmat) {
    __shared__ float X[64][64];  // 16 KB, reconstruction only
    const int lane = threadIdx.x;
    const int b = blockIdx.x;
    if (b >= nmat) return;
    const float* Sb = S + (size_t)b * 4096;
    float* Ob = Out + (size_t)b * 4096;

    // ---- load column `lane`: g[s] = S[s][lane] (coalesced across lanes)
    float g[64];
    #pragma unroll 64
    for (int s = 0; s < 64; ++s) g[s] = Sb[s * 64 + lane];

    float dpp = 0.0f;

    #pragma unroll 1
    for (int sweep = 0; sweep < NSWEEP_MAX; ++sweep) {
        // refresh Gram diagonal from actual column (kills drift)
        float d0 = 0.0f, d1 = 0.0f, d2 = 0.0f, d3 = 0.0f;
        #pragma unroll 16
        for (int s = 0; s < 64; s += 4) {
            d0 = fmaf(g[s], g[s], d0);
            d1 = fmaf(g[s + 1], g[s + 1], d1);
            d2 = fmaf(g[s + 2], g[s + 2], d2);
            d3 = fmaf(g[s + 3], g[s + 3], d3);
        }
        dpp = (d0 + d1) + (d2 + d3);

        // ---- initial pairing m = gray(1) = 1: direct fetch of partner copy
        float pr[64];
        #pragma unroll 64
        for (int s = 0; s < 64; ++s) pr[s] = dppf1<DPP_X1>(g[s]);
        float pd = dppf1<DPP_X1>(dpp);

        float maxt2 = 0.0f;
        #pragma unroll 1
        for (int i = 1; i < 64; ++i) {
            if (i > 1) {
                // re-pair: pr/pd currently hold l^m_prev; next partner is
                // l^m_cur = (l^m_prev)^delta -> XOR-delta permute.
                const int delta = i & (-i);
                switch (delta) {
                    case 1:
                        #pragma unroll
                        for (int s = 0; s < 64; ++s) pr[s] = dppf1<DPP_X1>(pr[s]);
                        pd = dppf1<DPP_X1>(pd);
                        break;
                    case 2:
                        #pragma unroll
                        for (int s = 0; s < 64; ++s) pr[s] = dppf1<DPP_X2>(pr[s]);
                        pd = dppf1<DPP_X2>(pd);
                        break;
                    case 4:  // XOR4 = XOR3 o XOR7
                        #pragma unroll
                        for (int s = 0; s < 64; ++s)
                            pr[s] = dppf1<DPP_X7>(dppf1<DPP_X3>(pr[s]));
                        pd = dppf1<DPP_X7>(dppf1<DPP_X3>(pd));
                        break;
                    case 8:
                        #pragma unroll
                        for (int s = 0; s < 64; ++s) pr[s] = dppf1<DPP_X8>(pr[s]);
                        pd = dppf1<DPP_X8>(pd);
                        break;
                    case 16:
                        #pragma unroll
                        for (int s = 0; s < 64; ++s) pr[s] = swap16_self(pr[s]);
                        pd = swap16_self(pd);
                        break;
                    default:  // 32
                        #pragma unroll
                        for (int s = 0; s < 64; ++s) pr[s] = swap32_self(pr[s]);
                        pd = swap32_self(pd);
                        break;
                }
            }
            const int m = i ^ (i >> 1);
            const int xl = lane ^ m;
            const bool isLow = lane < xl;
            // ---- lane-local Gram cross term (4-way split, pair-symmetric)
            float a0 = 0.0f, a1 = 0.0f, a2 = 0.0f, a3 = 0.0f;
            #pragma unroll 16
            for (int s = 0; s < 64; s += 4) {
                a0 = fmaf(g[s], pr[s], a0);
                a1 = fmaf(g[s + 1], pr[s + 1], a1);
                a2 = fmaf(g[s + 2], pr[s + 2], a2);
                a3 = fmaf(g[s + 3], pr[s + 3], a3);
            }
            const float dpq = (a0 + a1) + (a2 + a3);
            const float t2 = dpq * dpq * __builtin_amdgcn_rcpf(dpp * pd);
            maxt2 = fmaxf(maxt2, t2);
            // ---- wave-uniform skip when every pair in this round converged
            if (__all(t2 < T2_TOL)) continue;
            // ---- canonical rotation (identical bits on both lanes)
            const float d_lo = isLow ? dpp : pd;
            const float d_hi = isLow ? pd : dpp;
            const float tau = (d_hi - d_lo) * __builtin_amdgcn_rcpf(2.0f * dpq);
            const float sq = __builtin_amdgcn_sqrtf(fmaf(tau, tau, 1.0f));
            float tt = __builtin_amdgcn_rcpf(fabsf(tau) + sq);
            tt = copysignf(tt, tau);
            float cc = __builtin_amdgcn_rsqf(fmaf(tt, tt, 1.0f));
            float ss = tt * cc;
            const bool tiny = fabsf(dpq) < 1e-30f;
            cc = tiny ? 1.0f : cc;
            ss = tiny ? 0.0f : ss;
            tt = tiny ? 0.0f : tt;
            const float es = isLow ? -ss : ss;
            const float t_own = isLow ? tt : -tt;
            // diagonal updates (own exact; partner mirrors bitwise)
            const float pdn = fmaf(t_own, dpq, pd);
            dpp = fmaf(-t_own, dpq, dpp);
            pd = pdn;
            // ---- rotate own column AND maintain partner copy:
            //   g'  = cc*g  + es*pr        (own update)
            //   pr' = cc*pr - es*g_old     (== partner's own update, bitwise)
            #pragma unroll 64
            for (int s = 0; s < 64; ++s) {
                const float m1 = es * pr[s];
                const float m2 = es * g[s];
                g[s] = fmaf(cc, g[s], m1);
                pr[s] = fmaf(cc, pr[s], -m2);
            }
        }
        // ---- wave max of maxt2
        maxt2 = fmaxf(maxt2, __shfl_xor(maxt2, 1));
        maxt2 = fmaxf(maxt2, __shfl_xor(maxt2, 2));
        maxt2 = fmaxf(maxt2, __shfl_xor(maxt2, 4));
        maxt2 = fmaxf(maxt2, __shfl_xor(maxt2, 8));
        maxt2 = fmaxf(maxt2, __shfl_xor(maxt2, 16));
        maxt2 = fmaxf(maxt2, __shfl_xor(maxt2, 32));
        if (maxt2 < T2_TOL) break;  // wave-uniform
    }

    // ---- fresh column norm^2 -> eigenvalue; clamp matches ref (on lambda)
    float dfin = 0.0f;
    #pragma unroll 64
    for (int s = 0; s < 64; ++s) dfin = fmaf(g[s], g[s], dfin);
    const float w = 0.5f * logf(fmaxf(dfin, EPS2));
    const float rs = __builtin_amdgcn_rsqf(fmaxf(dfin, 1e-20f));

    // ---- reconstruction: O = U diag(w) U^T, U columns = g*rs
    #pragma unroll 64
    for (int s = 0; s < 64; ++s) X[s][lane] = g[s] * rs;  // lane-private col
    __syncthreads();
    float uw[64];
    {
        const float4* rowp = (const float4*)&X[lane][0];  // own row of U
        #pragma unroll 16
        for (int gq = 0; gq < 16; ++gq) {
            const float4 q = rowp[gq];
            uw[4 * gq + 0] = q.x;
            uw[4 * gq + 1] = q.y;
            uw[4 * gq + 2] = q.z;
            uw[4 * gq + 3] = q.w;
        }
    }
    #pragma unroll 64
    for (int c = 0; c < 64; ++c) uw[c] *= rdlane_f(w, c);
    #pragma unroll 2
    for (int i = 0; i < 64; ++i) {
        const float4* Urow = (const float4*)&X[i][0];  // wave-uniform: bcast
        float acc = 0.0f;
        #pragma unroll 16
        for (int gq = 0; gq < 16; ++gq) {
            const float4 q = Urow[gq];
            acc = fmaf(q.x, uw[4 * gq + 0], acc);
            acc = fmaf(q.y, uw[4 * gq + 1], acc);
            acc = fmaf(q.z, uw[4 * gq + 2], acc);
            acc = fmaf(q.w, uw[4 * gq + 3], acc);
        }
        Ob[i * 64 + lane] = acc;
    }
}

extern "C" void kernel_launch(void* const* d_in, const int* in_sizes, int n_in,
                              void* d_out, int out_size, void* d_ws, size_t ws_size,
                              hipStream_t stream) {
    const float* S = (const float*)d_in[0];
    float* Out = (float*)d_out;
    const int nmat = in_sizes[0] / 4096;
    spdlog_onesided<<<nmat, 64, 0, stream>>>(S, Out, nmat);
}